// Round 15
// baseline (615.559 us; speedup 1.0000x reference)
//
#include <hip/hip_runtime.h>

#define NTOK 16384
#define DIM  128
#define NMT  64    // number of 256-wide mega j-tiles
#define RB   64    // i-rows per attn block

typedef __attribute__((ext_vector_type(8))) short short8;
typedef __attribute__((ext_vector_type(4))) float f32x4;
typedef __attribute__((ext_vector_type(4))) int   i32x4;
typedef __attribute__((address_space(1))) void void_g;
typedef __attribute__((address_space(3))) void void_l;

// fold 1/sqrt(128) * log2(e) into Q so scores come out in log2 domain
#define QSCALE (1.4426950408889634f * 0.08838834764831845f)

__device__ __forceinline__ short f2bf(float f) {
  union { float f; unsigned u; } v; v.f = f;
  return (short)((v.u + 0x7FFFu + ((v.u >> 16) & 1u)) >> 16);
}

// packed f32x2 -> bf16x2, single VALU op
__device__ __forceinline__ unsigned pkbf2(float a, float b) {
  unsigned r;
  asm("v_cvt_pk_bf16_f32 %0, %1, %2" : "=v"(r) : "v"(a), "v"(b));
  return r;
}

__device__ __forceinline__ short8 pack8(const float4 a, const float4 b) {
  union { unsigned u[4]; short8 s; } r;
  r.u[0] = pkbf2(a.x, a.y);
  r.u[1] = pkbf2(a.z, a.w);
  r.u[2] = pkbf2(b.x, b.y);
  r.u[3] = pkbf2(b.z, b.w);
  return r.s;
}

__device__ __forceinline__ void gload16(char* l, const char* g) {
  __builtin_amdgcn_global_load_lds((void_g*)g, (void_l*)l, 16, 0, 0);
}

__device__ __forceinline__ float bf2f(short s) {
  union { float f; unsigned u; } v;
  v.u = ((unsigned)(unsigned short)s) << 16;
  return v.f;
}

// ---------------------------------------------------------------------------
// Kernel 1: QKV projection (identical to R13).
//  Qb: [N][128] bf16 row-major, pre-scaled by QSCALE
//  K3 (bf16): A-frag chunks, old-tile t = 32KB; chunk(jfg,kf)=1KB; lane l
//      holds K[t*128 + jfg*16 + (l&15)][kf*32 + (l>>4)*8 .. +8] at lane*16
//  V8 (fp8 e4m3), b128-paired: unit (t, sl, nfp, l15) = 16B holding
//      V[t*128+sl*8 ..+8][d=nfp*32+l15] (lo 8B) and [d=nfp*32+16+l15] (hi 8B)
// ---------------------------------------------------------------------------
__device__ __forceinline__ void mm16(const short8 (&af)[4], const float* __restrict__ W,
                                     const float* __restrict__ b, int l15, int lg,
                                     f32x4 (&acc)[8], float (&bias)[8]) {
#pragma unroll
  for (int nf = 0; nf < 8; ++nf) {
    acc[nf][0] = 0.f; acc[nf][1] = 0.f; acc[nf][2] = 0.f; acc[nf][3] = 0.f;
  }
#pragma unroll
  for (int kf = 0; kf < 4; ++kf) {
#pragma unroll
    for (int nf = 0; nf < 8; ++nf) {
      const float* wp = W + (size_t)(nf * 16 + l15) * DIM + kf * 32 + lg * 8;
      short8 bfr = pack8(*(const float4*)wp, *(const float4*)(wp + 4));
      acc[nf] = __builtin_amdgcn_mfma_f32_16x16x32_bf16(af[kf], bfr, acc[nf], 0, 0, 0);
    }
  }
#pragma unroll
  for (int nf = 0; nf < 8; ++nf) bias[nf] = b[nf * 16 + l15];
}

__global__ __launch_bounds__(256) void proj_kernel(
    const float* __restrict__ X,
    const float* __restrict__ Wq, const float* __restrict__ bq,
    const float* __restrict__ Wk, const float* __restrict__ bk,
    const float* __restrict__ Wv, const float* __restrict__ bv,
    short* __restrict__ Qb, char* __restrict__ K3, char* __restrict__ V8) {
  __shared__ short ktile[64][136];
  __shared__ short vtile[64][136];

  const int tid = threadIdx.x;
  const int w = tid >> 6, lane = tid & 63;
  const int l15 = lane & 15, lg = lane >> 4;
  const int i0 = blockIdx.x * 64;
  const int t = i0 >> 7, jl0 = i0 & 127;

  short8 af[4];
  {
    const int xrow = i0 + w * 16 + l15;
#pragma unroll
    for (int kf = 0; kf < 4; ++kf) {
      const float* xp = X + (size_t)xrow * DIM + kf * 32 + lg * 8;
      af[kf] = pack8(*(const float4*)xp, *(const float4*)(xp + 4));
    }
  }

  f32x4 acc[8];
  float bias[8];

  // ---- Q ----
  mm16(af, Wq, bq, l15, lg, acc, bias);
#pragma unroll
  for (int nf = 0; nf < 8; ++nf) {
    const int d = nf * 16 + l15;
#pragma unroll
    for (int rr = 0; rr < 4; ++rr) {
      const int i = i0 + w * 16 + lg * 4 + rr;
      Qb[(size_t)i * DIM + d] = f2bf((acc[nf][rr] + bias[nf]) * QSCALE);
    }
  }

  // ---- K ----
  mm16(af, Wk, bk, l15, lg, acc, bias);
#pragma unroll
  for (int nf = 0; nf < 8; ++nf) {
    const int d = nf * 16 + l15;
#pragma unroll
    for (int rr = 0; rr < 4; ++rr)
      ktile[w * 16 + lg * 4 + rr][d] = f2bf(acc[nf][rr] + bias[nf]);
  }

  // ---- V ----
  mm16(af, Wv, bv, l15, lg, acc, bias);
#pragma unroll
  for (int nf = 0; nf < 8; ++nf) {
    const int d = nf * 16 + l15;
#pragma unroll
    for (int rr = 0; rr < 4; ++rr)
      vtile[w * 16 + lg * 4 + rr][d] = f2bf(acc[nf][rr] + bias[nf]);
  }
  __syncthreads();

  // K3 chunks (bf16): task = chunk o (0..15) x local row (0..63)
#pragma unroll
  for (int it = 0; it < 4; ++it) {
    const int task = it * 256 + tid;
    const int o = task >> 6, jr = task & 63;
    const int j = i0 + jr;
    const int jfg = (j >> 4) & 7;
    const int kf = o >> 2, lgc = o & 3;
    short8 st = *(const short8*)&ktile[jr][o * 8];
    *(short8*)(K3 + ((size_t)((t * 8 + jfg) * 4 + kf) << 10) + lgc * 256 + (j & 15) * 16) = st;
  }

  // V8 chunks (fp8, b128-paired): task = c (8 j-octets) x d (128)
#pragma unroll
  for (int it = 0; it < 4; ++it) {
    const int task = it * 256 + tid;
    const int c = task >> 7, d = task & 127;
    float f[8];
#pragma unroll
    for (int s2 = 0; s2 < 8; ++s2) f[s2] = bf2f(vtile[c * 8 + s2][d]);
    int lo = __builtin_amdgcn_cvt_pk_fp8_f32(f[0], f[1], 0, false);
    lo = __builtin_amdgcn_cvt_pk_fp8_f32(f[2], f[3], lo, true);
    int hi = __builtin_amdgcn_cvt_pk_fp8_f32(f[4], f[5], 0, false);
    hi = __builtin_amdgcn_cvt_pk_fp8_f32(f[6], f[7], hi, true);
    const int sl = (jl0 >> 3) + c;     // j-octet index within old tile (0..15)
    const int nfp = d >> 5, hi8 = (d >> 4) & 1, dl = d & 15;
    *(int2*)(V8 + (((size_t)(t * 16 + sl) * 64 + nfp * 16 + dl) * 16) + hi8 * 8)
        = make_int2(lo, hi);
  }
}

// ---------------------------------------------------------------------------
// Kernel 2: fused masked-softmax attention, BJ=256 mega-steps (64 iters).
// 256 blocks x 512 threads (8 waves, 2 waves/SIMD).
// Wave (ir, wc): i-rows [ir*32,+32) (f=0,1), j-slice [wc*64,+64) per mega.
// K mega-tile (64KB bf16) LDS double-buffered via global_load_lds.
// adj: each wave ballot-compresses 8 rows (1KB contiguous loads) into 32B
// of bits/row -> 2KB LDS double buffer. V (fp8 paired) regs from L2.
// Softmax in-register (swapped QK^T + bpermute); fp8 PV (P halved).
// ---------------------------------------------------------------------------
__device__ __forceinline__ void mega_step(
    int T, const char* kcur, const char* acur, char* knxt, char* anxt,
    const char* __restrict__ K3, const char* __restrict__ V8,
    const int* __restrict__ adj,
    const short8 (&qf)[2][4], f32x4 (&acc)[2][8], float (&dsum)[2],
    int i0, int ir, int wc, int l15, int lg, int lane, int w, int tid,
    int ad0, bool selhi) {
  const int Tn = (T + 1) & (NMT - 1);

  // 1. stage K mega-tile T+1 (64KB DMA, lands by the end-of-step barrier)
  {
    const char* gk = K3 + ((size_t)Tn << 16);
#pragma unroll
    for (int it = 0; it < 8; ++it)
      gload16(knxt + it * 8192 + tid * 16, gk + it * 8192 + tid * 16);
  }

  // 2. adj rows for T+1: 1KB contiguous per row (optimal DRAM pattern)
  i32x4 arow[8];
#pragma unroll
  for (int q = 0; q < 8; ++q)
    arow[q] = *(const i32x4*)(adj + (size_t)(i0 + w * 8 + q) * NTOK + Tn * 256 + lane * 4);

  // 3. V(T) fragments (L2; latency hides under QK)
  i32x4 vfr[2][4];
  {
    const int ot = T * 2 + (wc >> 1);
#pragma unroll
    for (int sb = 0; sb < 2; ++sb)
#pragma unroll
      for (int nfp = 0; nfp < 4; ++nfp) {
        const int sl = (wc & 1) * 8 + sb * 4 + lg;
        vfr[sb][nfp] = *(const i32x4*)(V8 + ((size_t)((ot * 16 + sl) * 64 + nfp * 16 + l15) * 16));
      }
  }

  // 4a. bits(T) from LDS: per f-row, 32B = {b0,b1}{b2,b3}
  i32x4 qa[2], qb[2];
#pragma unroll
  for (int f = 0; f < 2; ++f) {
    const int row = ir * 32 + f * 16 + l15;
    qa[f] = *(const i32x4*)(acur + row * 32);
    qb[f] = *(const i32x4*)(acur + row * 32 + 16);
  }

  // 4b. S^T = K @ Q^T : lane holds S[i=l15][j = wc*64 + jf*16 + lg*4 + r]
  f32x4 sT[2][4];
#pragma unroll
  for (int f = 0; f < 2; ++f)
#pragma unroll
    for (int jf = 0; jf < 4; ++jf) {
      sT[f][jf][0] = 0.f; sT[f][jf][1] = 0.f; sT[f][jf][2] = 0.f; sT[f][jf][3] = 0.f;
    }
#pragma unroll
  for (int jf = 0; jf < 4; ++jf) {
    const int u = wc * 4 + jf;
#pragma unroll
    for (int kf = 0; kf < 4; ++kf) {
      const short8 kfr = *(const short8*)(kcur + (u >> 3) * 32768 + (((u & 7) * 4 + kf) << 10) + lane * 16);
#pragma unroll
      for (int f = 0; f < 2; ++f)
        sT[f][jf] = __builtin_amdgcn_mfma_f32_16x16x32_bf16(kfr, qf[f][kf], sT[f][jf], 0, 0, 0);
    }
  }

  // 5. ballots(T+1) + write bit rows to anxt (arow loads have landed by now)
#pragma unroll
  for (int q = 0; q < 8; ++q) {
    const unsigned long long b0 = __ballot(arow[q][0] != 0);
    const unsigned long long b1 = __ballot(arow[q][1] != 0);
    const unsigned long long b2 = __ballot(arow[q][2] != 0);
    const unsigned long long b3 = __ballot(arow[q][3] != 0);
    if (lane < 2) {
      i32x4 o;
      o[0] = lane ? (int)b2 : (int)b0;
      o[1] = lane ? (int)(b2 >> 32) : (int)(b0 >> 32);
      o[2] = lane ? (int)b3 : (int)b1;
      o[3] = lane ? (int)(b3 >> 32) : (int)(b1 >> 32);
      *(i32x4*)(anxt + (w * 8 + q) * 32 + lane * 16) = o;
    }
  }

  // 6. mask + exp2 (halved: fp8 e4m3 max 448) + row-sum + fp8 pack
  const int hi2 = wc >> 1;
  const int sh0 = (wc & 1) * 16 + lg;
  int pk8[2][4];
#pragma unroll
  for (int f = 0; f < 2; ++f)
#pragma unroll
    for (int jf = 0; jf < 4; ++jf) {
      const int sh = sh0 + jf * 4;
      const unsigned d0 = ((unsigned)qa[f][hi2] >> sh) & 1;
      const unsigned d1 = ((unsigned)qa[f][2 + hi2] >> sh) & 1;
      const unsigned d2 = ((unsigned)qb[f][hi2] >> sh) & 1;
      const unsigned d3 = ((unsigned)qb[f][2 + hi2] >> sh) & 1;
      const float p0 = d0 ? __builtin_exp2f(sT[f][jf][0]) * 0.5f : 0.5f;
      const float p1 = d1 ? __builtin_exp2f(sT[f][jf][1]) * 0.5f : 0.5f;
      const float p2 = d2 ? __builtin_exp2f(sT[f][jf][2]) * 0.5f : 0.5f;
      const float p3 = d3 ? __builtin_exp2f(sT[f][jf][3]) * 0.5f : 0.5f;
      dsum[f] += (p0 + p1) + (p2 + p3);
      int t0 = __builtin_amdgcn_cvt_pk_fp8_f32(p0, p1, 0, false);
      pk8[f][jf] = __builtin_amdgcn_cvt_pk_fp8_f32(p2, p3, t0, true);
    }

  // 7. per 32-j slab: bpermute exchange + fp8 PV
#pragma unroll
  for (int sb = 0; sb < 2; ++sb) {
    union { int2 i2; long l; } pa[2];
#pragma unroll
    for (int f = 0; f < 2; ++f)
#pragma unroll
      for (int w2 = 0; w2 < 2; ++w2) {
        const int addr = ad0 + w2 * 64;
        const int r0 = __builtin_amdgcn_ds_bpermute(addr, pk8[f][sb * 2]);
        const int r1 = __builtin_amdgcn_ds_bpermute(addr, pk8[f][sb * 2 + 1]);
        (w2 ? pa[f].i2.y : pa[f].i2.x) = selhi ? r1 : r0;
      }
#pragma unroll
    for (int nfp = 0; nfp < 4; ++nfp) {
      union { i32x4 v; long l[2]; } vv; vv.v = vfr[sb][nfp];
#pragma unroll
      for (int f = 0; f < 2; ++f) {
        acc[f][nfp * 2]     = __builtin_amdgcn_mfma_f32_16x16x32_fp8_fp8(pa[f].l, vv.l[0], acc[f][nfp * 2], 0, 0, 0);
        acc[f][nfp * 2 + 1] = __builtin_amdgcn_mfma_f32_16x16x32_fp8_fp8(pa[f].l, vv.l[1], acc[f][nfp * 2 + 1], 0, 0, 0);
      }
    }
  }

  // 8. barrier: staged K + bit rows complete, buffers flip
  __syncthreads();
}

__global__ __launch_bounds__(512, 2) void attn_kernel(
    const short* __restrict__ QbG, const char* __restrict__ K3,
    const char* __restrict__ V8, const int* __restrict__ adj,
    float* __restrict__ out) {
  __shared__ __align__(16) char kbuf[2][65536];   // K bf16 mega double buffer
  __shared__ __align__(16) char abit[2][2048];    // packed adj bits dbuf
  __shared__ float denp[4][64];

  const int tid = threadIdx.x;
  const int w = tid >> 6, lane = tid & 63;
  const int l15 = lane & 15, lg = lane >> 4;
  const int ir = w >> 2, wc = w & 3;
  const int i0 = blockIdx.x * RB;

  // bpermute source lane for (w2): lg_src = (lg*2 + w2) & 3; jf-half by lg>=2
  const int ad0 = 4 * (l15 + 16 * ((lg * 2) & 3));
  const bool selhi = (lg & 2) != 0;

  // Q B-frags: lane holds Q[i = i0+ir*32+f*16+l15][kf*32+lg*8 ..+8]
  short8 qf[2][4];
#pragma unroll
  for (int f = 0; f < 2; ++f) {
    const int i = i0 + ir * 32 + f * 16 + l15;
#pragma unroll
    for (int kf = 0; kf < 4; ++kf)
      qf[f][kf] = *(const short8*)(QbG + (size_t)i * DIM + kf * 32 + lg * 8);
  }

  f32x4 acc[2][8];
#pragma unroll
  for (int f = 0; f < 2; ++f)
#pragma unroll
    for (int nf = 0; nf < 8; ++nf) {
      acc[f][nf][0] = 0.f; acc[f][nf][1] = 0.f; acc[f][nf][2] = 0.f; acc[f][nf][3] = 0.f;
    }
  float dsum[2] = {0.f, 0.f};

  // prologue: stage K mega 0; ballot-compress adj mega 0
  {
    const char* gk = K3;
#pragma unroll
    for (int it = 0; it < 8; ++it)
      gload16(kbuf[0] + it * 8192 + tid * 16, gk + it * 8192 + tid * 16);
#pragma unroll
    for (int q = 0; q < 8; ++q) {
      const i32x4 v = *(const i32x4*)(adj + (size_t)(i0 + w * 8 + q) * NTOK + lane * 4);
      const unsigned long long b0 = __ballot(v[0] != 0);
      const unsigned long long b1 = __ballot(v[1] != 0);
      const unsigned long long b2 = __ballot(v[2] != 0);
      const unsigned long long b3 = __ballot(v[3] != 0);
      if (lane < 2) {
        i32x4 o;
        o[0] = lane ? (int)b2 : (int)b0;
        o[1] = lane ? (int)(b2 >> 32) : (int)(b0 >> 32);
        o[2] = lane ? (int)b3 : (int)b1;
        o[3] = lane ? (int)(b3 >> 32) : (int)(b1 >> 32);
        *(i32x4*)(abit[0] + (w * 8 + q) * 32 + lane * 16) = o;
      }
    }
  }
  __syncthreads();

  for (int T = 0; T < NMT; T += 2) {
    mega_step(T,     kbuf[0], abit[0], kbuf[1], abit[1], K3, V8, adj, qf, acc,
              dsum, i0, ir, wc, l15, lg, lane, w, tid, ad0, selhi);
    mega_step(T + 1, kbuf[1], abit[1], kbuf[0], abit[0], K3, V8, adj, qf, acc,
              dsum, i0, ir, wc, l15, lg, lane, w, tid, ad0, selhi);
  }

  // ---- denominator: lane covers i per f; sum over lg groups, then wc ----
#pragma unroll
  for (int f = 0; f < 2; ++f) {
    float v = dsum[f];
    v += __shfl_xor(v, 16);
    v += __shfl_xor(v, 32);
    if (lg == 0) denp[wc][ir * 32 + f * 16 + l15] = v;
  }

  // ---- cross-wc acc reduction through LDS (reuse kbuf) ----
  float* red = (float*)kbuf;   // 2 ir-slots x 32 rows x 132 floats
#pragma unroll
  for (int rnd = 1; rnd <= 3; ++rnd) {
    __syncthreads();
    if (wc == rnd) {
      const int base = ir * 32 * 132;
#pragma unroll
      for (int f = 0; f < 2; ++f)
#pragma unroll
        for (int nf = 0; nf < 8; ++nf)
#pragma unroll
          for (int r = 0; r < 4; ++r)
            red[base + (f * 16 + lg * 4 + r) * 132 + nf * 16 + l15] = acc[f][nf][r];
    }
    __syncthreads();
    if (wc == 0) {
      const int base = ir * 32 * 132;
#pragma unroll
      for (int f = 0; f < 2; ++f)
#pragma unroll
        for (int nf = 0; nf < 8; ++nf)
#pragma unroll
          for (int r = 0; r < 4; ++r)
            acc[f][nf][r] += red[base + (f * 16 + lg * 4 + r) * 132 + nf * 16 + l15];
    }
  }

  if (wc == 0) {
#pragma unroll
    for (int f = 0; f < 2; ++f) {
      float den[4];
#pragma unroll
      for (int r = 0; r < 4; ++r) {
        const int il = ir * 32 + f * 16 + lg * 4 + r;
        den[r] = (denp[0][il] + denp[1][il]) + (denp[2][il] + denp[3][il]);
      }
#pragma unroll
      for (int nf = 0; nf < 8; ++nf)
#pragma unroll
        for (int r = 0; r < 4; ++r) {
          const int i = ir * 32 + f * 16 + lg * 4 + r;
          out[(size_t)(i0 + i) * DIM + nf * 16 + l15] = acc[f][nf][r] / den[r];
        }
    }
  }
}

// ---------------------------------------------------------------------------
extern "C" void kernel_launch(void* const* d_in, const int* in_sizes, int n_in,
                              void* d_out, int out_size, void* d_ws, size_t ws_size,
                              hipStream_t stream) {
  const float* X  = (const float*)d_in[0];
  const float* Wq = (const float*)d_in[1];
  const float* bq = (const float*)d_in[2];
  const float* Wk = (const float*)d_in[3];
  const float* bk = (const float*)d_in[4];
  const float* Wv = (const float*)d_in[5];
  const float* bv = (const float*)d_in[6];
  const int*  adj = (const int*)d_in[7];
  float* out = (float*)d_out;

  char* ws = (char*)d_ws;
  short* Qb = (short*)ws;                       // 4 MB bf16 [N][128]
  char*  K3 = ws + ((size_t)4 << 20);           // 4 MB A-frag-contiguous K (bf16)
  char*  V8 = ws + ((size_t)8 << 20);           // 2 MB fp8 V^T paired chunks

  proj_kernel<<<256, 256, 0, stream>>>(X, Wq, bq, Wk, bk, Wv, bv, Qb, K3, V8);
  attn_kernel<<<256, 512, 0, stream>>>(Qb, K3, V8, adj, out);
}